// Round 11
// baseline (970.767 us; speedup 1.0000x reference)
//
#include <hip/hip_runtime.h>

#define BATCH 8
#define NPTS  2048
#define TPB   512           // 8 waves/WG, 2 WG/CU (LDS 64KB x2 <= 160KB), 4 waves/SIMD
#define WGB   64            // workgroups per batch
#define NWG   (BATCH*WGB)   // 512 = exact residency capacity
#define ITERS 50
#define R     4

#define KLOG2E    1442.6950408889634f    // log2(e)/eps
#define TWO_K     2885.3900817779268f    // 2*log2(e)/eps
#define INV_TK    3.4657359027997264e-4f // 1/(2k)
#define INV_K     6.931471805599453e-4f  // 1/k = eps*ln2
#define INV_2K_SQ 1.2011325347955035e-7f // 1/(2k)^2
#define AR_SCALE  -1.7328679513998632e-4f// -k/(2k)^2 = -1/(4k)
#define NEGU      -1e30f
#define BIGD      1e10f

typedef float f2 __attribute__((ext_vector_type(2)));

__device__ __forceinline__ float exp2fast(float x) { return __builtin_amdgcn_exp2f(x); }
__device__ __forceinline__ float log2fast(float x) { return __builtin_amdgcn_logf(x); }
__device__ __forceinline__ float clipf(float v)    { return fminf(fmaxf(v, -1.0f), 1.0f); }
__device__ __forceinline__ f2 bc(float x) { f2 r; r.x = x; r.y = x; return r; }

// packed fp32: ALL operands are 64-bit VGPR pairs on gfx950
__device__ __forceinline__ f2 pk_fma(f2 a, f2 b, f2 c) {
    f2 d;
    asm("v_pk_fma_f32 %0, %1, %2, %3" : "=v"(d) : "v"(a), "v"(b), "v"(c));
    return d;
}
__device__ __forceinline__ f2 pk_add(f2 a, f2 b) {
    f2 d;
    asm("v_pk_add_f32 %0, %1, %2" : "=v"(d) : "v"(a), "v"(b));
    return d;
}

// relaxed agent-scope atomics: coherent at LLC (cache-bypassing), no fences
__device__ __forceinline__ float aloadf(const float* p) {
    return __hip_atomic_load(p, __ATOMIC_RELAXED, __HIP_MEMORY_SCOPE_AGENT);
}
__device__ __forceinline__ void astoref(float* p, float v) {
    __hip_atomic_store(p, v, __ATOMIC_RELAXED, __HIP_MEMORY_SCOPE_AGENT);
}
__device__ __forceinline__ int aloadi(const int* p) {
    return __hip_atomic_load(p, __ATOMIC_RELAXED, __HIP_MEMORY_SCOPE_AGENT);
}
__device__ __forceinline__ void astorei(int* p, int v) {
    __hip_atomic_store(p, v, __ATOMIC_RELAXED, __HIP_MEMORY_SCOPE_AGENT);
}
__device__ __forceinline__ f2 aloadf2(const float* p) {
    unsigned long long v = __hip_atomic_load((const unsigned long long*)p,
                                             __ATOMIC_RELAXED, __HIP_MEMORY_SCOPE_AGENT);
    union { unsigned long long u; f2 f; } c; c.u = v; return c.f;
}

__device__ __forceinline__ float wsum(float v) {
#pragma unroll
    for (int d = 1; d < 64; d <<= 1) v += __shfl_xor(v, d);
    return v;
}
__device__ __forceinline__ float wmax(float v) {
#pragma unroll
    for (int d = 1; d < 64; d <<= 1) v = fmaxf(v, __shfl_xor(v, d));
    return v;
}
__device__ __forceinline__ float wmin(float v) {
#pragma unroll
    for (int d = 1; d < 64; d <<= 1) v = fminf(v, __shfl_xor(v, d));
    return v;
}

// Wave 0 observes ALL per-producer-wave flags of one side (512 ints, lane-major
// coalesced: lane reads flags[lane + 64k], k=0..7). Row-groups >= cntv never
// publish (rows out of range) and are masked. Other waves proceed to the
// following __syncthreads, which broadcasts the result.
__device__ __forceinline__ void wavepoll(const int* __restrict__ flags,
                                         int target, int cntv, int wv, int lane)
{
    if (wv != 0) return;
    for (;;) {
        int mn = target;
#pragma unroll
        for (int k = 0; k < 8; ++k) {
            int idx = lane + (k << 6);
            int v = (idx < cntv) ? aloadi(&flags[idx]) : target;
            mn = min(mn, v);
        }
        if (__all(mn >= target)) break;
        __builtin_amdgcn_s_sleep(2);
    }
}

// One Sinkhorn half-iteration (packed-pair LSE over planar f2 LDS columns).
// Computes uv[R] = L2C - LSE2 for this wave's R rows; returns false if the
// wave's rows are out of range. Persistent log2 ref L[] + drift D[]; exact
// two-pass redo on seed (iter 0) / NaN / blowup.
__device__ __forceinline__ bool half_fused_pk(
    const f2* __restrict__ cx, const f2* __restrict__ cy,
    const f2* __restrict__ cz, const f2* __restrict__ cw,
    const f2* __restrict__ rx, const f2* __restrict__ ry, const f2* __restrict__ rz,
    float L2C, float* L, float* D, float* uv,
    int nrows, int ncols, int r0, int lane)
{
    if (r0 >= nrows) return false;
    const int nst = (ncols + 127) >> 7;   // 128 cols/step
    const int rp = r0 >> 1;
    f2 vx0 = rx[rp], vx1 = rx[rp + 1];
    f2 vy0 = ry[rp], vy1 = ry[rp + 1];
    f2 vz0 = rz[rp], vz1 = rz[rp + 1];
    f2 x0p[R] = { bc(vx0.x * INV_TK), bc(vx0.y * INV_TK), bc(vx1.x * INV_TK), bc(vx1.y * INV_TK) };
    f2 x1p[R] = { bc(vy0.x * INV_TK), bc(vy0.y * INV_TK), bc(vy1.x * INV_TK), bc(vy1.y * INV_TK) };
    f2 x2p[R] = { bc(vz0.x * INV_TK), bc(vz0.y * INV_TK), bc(vz1.x * INV_TK), bc(vz1.y * INV_TK) };

    float Lp[R];
    f2 nLp[R];
#pragma unroll
    for (int r = 0; r < R; ++r) { Lp[r] = L[r] + D[r]; nLp[r] = bc(-Lp[r]); }

    float S0[R], S1[R];
#pragma unroll
    for (int r = 0; r < R; ++r) { S0[r] = 0.0f; S1[r] = 0.0f; }

    for (int s = 0; s < nst; ++s) {
        int p = (s << 6) + lane;
        f2 bx = cx[p], by = cy[p], bz = cz[p], bw = cw[p];
#pragma unroll
        for (int r = 0; r < R; ++r) {
            f2 t = pk_fma(x2p[r], bz, bw);
            t = pk_fma(x1p[r], by, t);
            t = pk_fma(x0p[r], bx, t);
            t = pk_add(nLp[r], t);
            S0[r] += exp2fast(t.x);
            S1[r] += exp2fast(t.y);
        }
    }

    float Ssum[R];
    bool redo = false;
#pragma unroll
    for (int r = 0; r < R; ++r) {
        Ssum[r] = wsum(S0[r] + S1[r]);
        redo |= !(Ssum[r] >= 1e-30f && Ssum[r] <= 1e30f);   // 0/inf/NaN/drift
    }
    if (redo) {   // wave-uniform exact two-pass recompute
        float Mn[R];
#pragma unroll
        for (int r = 0; r < R; ++r) Mn[r] = -3.0e38f;
        for (int s = 0; s < nst; ++s) {
            int p = (s << 6) + lane;
            f2 bx = cx[p], by = cy[p], bz = cz[p], bw = cw[p];
#pragma unroll
            for (int r = 0; r < R; ++r) {
                f2 t = pk_fma(x2p[r], bz, bw);
                t = pk_fma(x1p[r], by, t);
                t = pk_fma(x0p[r], bx, t);
                Mn[r] = fmaxf(Mn[r], fmaxf(t.x, t.y));
            }
        }
#pragma unroll
        for (int r = 0; r < R; ++r) {
            Lp[r] = wmax(Mn[r]); nLp[r] = bc(-Lp[r]);
            S0[r] = 0.0f; S1[r] = 0.0f;
        }
        for (int s = 0; s < nst; ++s) {
            int p = (s << 6) + lane;
            f2 bx = cx[p], by = cy[p], bz = cz[p], bw = cw[p];
#pragma unroll
            for (int r = 0; r < R; ++r) {
                f2 t = pk_fma(x2p[r], bz, bw);
                t = pk_fma(x1p[r], by, t);
                t = pk_fma(x0p[r], bx, t);
                t = pk_add(nLp[r], t);
                S0[r] += exp2fast(t.x);
                S1[r] += exp2fast(t.y);
            }
        }
#pragma unroll
        for (int r = 0; r < R; ++r) Ssum[r] = wsum(S0[r] + S1[r]);
    }

#pragma unroll
    for (int r = 0; r < R; ++r) {
        float lnew = Lp[r] + log2fast(Ssum[r]);          // exact LSE2
        D[r] = (L[r] > 1.0e37f) ? 0.0f : (lnew - L[r]);  // drift (0 on seed)
        L[r] = lnew;
        uv[r] = L2C - lnew;                              // u-domain output
    }
    return true;
}

__launch_bounds__(TPB, 4)   // 4 waves/SIMD -> 128 VGPR cap, guarantees 2 WG/CU
__global__ void pcl_kernel(const float* __restrict__ pred,
                           const float* __restrict__ gt,
                           const int* __restrict__ nlen,
                           const int* __restrict__ mlen,
                           int* __restrict__ hdr,
                           float* __restrict__ fbuf,
                           float* __restrict__ gbuf,
                           float* __restrict__ parts,
                           float* __restrict__ bres,
                           float* __restrict__ out)
{
    // planar geometry (6 x 8KB) + double-buffered staging planes (2 x 8KB) = 64KB
    __shared__ f2 XSX[NPTS/2], XSY[NPTS/2], XSZ[NPTS/2];
    __shared__ f2 YSX[NPTS/2], YSY[NPTS/2], YSZ[NPTS/2];
    __shared__ float4 XW[TPB], YW[TPB];   // u_f / u_g staging

    const int tid  = threadIdx.x;
    const int wg   = blockIdx.x;
    // co-resident WG pair (wg, wg+256) -> DIFFERENT batches (stall overlap)
    const int lo   = wg & 255;
    const int hi   = wg >> 8;
    const int b    = ((lo & 7) + hi) & 7;
    const int wloc = (lo >> 3) + hi * 32;     // 0..63 within batch
    const int wv   = tid >> 6;                // 0..7
    const int lane = tid & 63;
    const int r0   = wloc * 32 + wv * R;      // first row (0..2044)
    const int rg   = wloc * 8 + wv;           // producer-wave id (0..511)
    const int j0   = tid << 2;                // this thread's 4 staged columns
    const int n = nlen[b];
    const int m = mlen[b];
    const float nf = (float)n, mf = (float)m;
    const int cvn = (n + 3) >> 2;             // valid producer-wave counts
    const int cvm = (m + 3) >> 2;
    const float* predb = pred + (size_t)b * NPTS * 3;
    const float* gtb   = gt   + (size_t)b * NPTS * 3;
    float* fb = fbuf + b * NPTS;      // u-domain f
    float* gb = gbuf + b * NPTS;      // u-domain g
    int* flagF = hdr + b * 512;       // per-producer-wave epochs (monotone)
    int* flagG = hdr + 4096 + b * 512;
    int* cntb  = hdr + 8192 + b * 16; // own 64B line
    int* done  = hdr + 8320;

    // stage scaled clipped geometry into planar LDS
    for (int idx = tid; idx < NPTS; idx += TPB) {
        const float* p = predb + (size_t)idx * 3;
        ((float*)XSX)[idx] = clipf(p[0]) * TWO_K;
        ((float*)XSY)[idx] = clipf(p[1]) * TWO_K;
        ((float*)XSZ)[idx] = clipf(p[2]) * TWO_K;
        const float* q = gtb + (size_t)idx * 3;
        ((float*)YSX)[idx] = clipf(q[0]) * TWO_K;
        ((float*)YSY)[idx] = clipf(q[1]) * TWO_K;
        ((float*)YSZ)[idx] = clipf(q[2]) * TWO_K;
    }
    __syncthreads();

    const float L2M = log2fast(mf);
    const float L2N = log2fast(nf);

    float Lf[R], Lg[R], Df[R], Dg[R];
#pragma unroll
    for (int r = 0; r < R; ++r) {
        Lf[r] = 3.0e38f; Lg[r] = 3.0e38f;   // sentinel: exact redo at iter 0
        Df[r] = 0.0f;    Dg[r] = 0.0f;
    }
    float uv[R];

    for (int it = 0; it < ITERS; ++it) {
        // ---- wait for g^it, stage into YW (iter 0: derive g==0 locally) ----
        if (it > 0) wavepoll(flagG, it, cvm, wv, lane);
        __syncthreads();                       // broadcast poll result; YW free
        {
            float4 w;
            if (it == 0) {
                f2 gx0 = YSX[2*tid],   gy0 = YSY[2*tid],   gz0 = YSZ[2*tid];
                f2 gx1 = YSX[2*tid+1], gy1 = YSY[2*tid+1], gz1 = YSZ[2*tid+1];
                f2 s0 = gx0*gx0 + gy0*gy0 + gz0*gz0;
                f2 s1 = gx1*gx1 + gy1*gy1 + gz1*gz1;
                w.x = s0.x * AR_SCALE; w.y = s0.y * AR_SCALE;
                w.z = s1.x * AR_SCALE; w.w = s1.y * AR_SCALE;
            } else {
                f2 a = aloadf2(&gb[j0]);
                f2 c = aloadf2(&gb[j0 + 2]);
                w.x = a.x; w.y = a.y; w.z = c.x; w.w = c.y;
            }
            if (j0 + 3 >= m) {   // mask padded columns
                if (j0     >= m) w.x = NEGU;
                if (j0 + 1 >= m) w.y = NEGU;
                if (j0 + 2 >= m) w.z = NEGU;
                w.w = NEGU;
            }
            YW[tid] = w;
        }
        __syncthreads();
        if (half_fused_pk(YSX, YSY, YSZ, (const f2*)YW, XSX, XSY, XSZ,
                          L2M, Lf, Df, uv, n, m, r0, lane)) {   // f = update(g)
            float v = uv[0];
#pragma unroll
            for (int r = 1; r < R; ++r) v = (lane == r) ? uv[r] : v;
            if (lane < R && (r0 + lane) < n) astoref(&fb[r0 + lane], v);
            asm volatile("s_waitcnt vmcnt(0)" ::: "memory");   // own stores at LLC
            if (lane == 0) astorei(&flagF[rg], it + 1);        // wave-autonomous publish
        }

        // ---- wait for f^{it+1}, stage into XW ----
        wavepoll(flagF, it + 1, cvn, wv, lane);
        __syncthreads();                       // XW free (prev compute g done)
        {
            f2 a = aloadf2(&fb[j0]);
            f2 c = aloadf2(&fb[j0 + 2]);
            float4 w;
            w.x = a.x; w.y = a.y; w.z = c.x; w.w = c.y;
            if (j0 + 3 >= n) {
                if (j0     >= n) w.x = NEGU;
                if (j0 + 1 >= n) w.y = NEGU;
                if (j0 + 2 >= n) w.z = NEGU;
                w.w = NEGU;
            }
            XW[tid] = w;
        }
        __syncthreads();
        if (half_fused_pk(XSX, XSY, XSZ, (const f2*)XW, YSX, YSY, YSZ,
                          L2N, Lg, Dg, uv, m, n, r0, lane)) {   // g = update(f)
            float v = uv[0];
#pragma unroll
            for (int r = 1; r < R; ++r) v = (lane == r) ? uv[r] : v;
            if (lane < R && (r0 + lane) < m) astoref(&gb[r0 + lane], v);
            asm volatile("s_waitcnt vmcnt(0)" ::: "memory");
            if (lane == 0) astorei(&flagG[rg], it + 1);
        }
    }

    // ---- stage final u_g for the cost pass ----
    wavepoll(flagG, ITERS, cvm, wv, lane);
    __syncthreads();
    {
        f2 a = aloadf2(&gb[j0]);
        f2 c = aloadf2(&gb[j0 + 2]);
        float4 w;
        w.x = a.x; w.y = a.y; w.z = c.x; w.w = c.y;
        if (j0 + 3 >= m) {
            if (j0     >= m) w.x = NEGU;
            if (j0 + 1 >= m) w.y = NEGU;
            if (j0 + 2 >= m) w.z = NEGU;
            w.w = NEGU;
        }
        YW[tid] = w;
    }
    __syncthreads();

    // ---- pass A: transport cost + chamfer x->y ----
    float wcost = 0.0f, chx = 0.0f;
    if (r0 < n) {
        const f2* YWf = (const f2*)YW;
        const int rp = r0 >> 1;
        f2 vx0 = XSX[rp], vx1 = XSX[rp + 1];
        f2 vy0 = XSY[rp], vy1 = XSY[rp + 1];
        f2 vz0 = XSZ[rp], vz1 = XSZ[rp + 1];
        float px0[R] = { vx0.x * INV_TK, vx0.y * INV_TK, vx1.x * INV_TK, vx1.y * INV_TK };
        float px1[R] = { vy0.x * INV_TK, vy0.y * INV_TK, vy1.x * INV_TK, vy1.y * INV_TK };
        float px2[R] = { vz0.x * INV_TK, vz0.y * INV_TK, vz1.x * INV_TK, vz1.y * INV_TK };
        float pxx[R], hrow[R];
        f2 dmn[R];
#pragma unroll
        for (int r = 0; r < R; ++r) {
            float sx = px0[r] * TWO_K, sy = px1[r] * TWO_K, sz = px2[r] * TWO_K;
            pxx[r] = fmaf(sx, sx, fmaf(sy, sy, sz * sz)) * INV_2K_SQ;
            hrow[r] = (r0 + r < n) ? aloadf(&fb[r0 + r]) : NEGU;   // u_f directly
            dmn[r].x = BIGD; dmn[r].y = BIGD;
        }
        const int nst = (m + 127) >> 7;
        for (int s = 0; s < nst; ++s) {
            int p = (s << 6) + lane;
            f2 bx = YSX[p], by = YSY[p], bz = YSZ[p], bw = YWf[p];
            f2 yy2 = (bx * bx + by * by + bz * bz) * INV_2K_SQ;
            bool jv0 = (2 * p)     < m;
            bool jv1 = (2 * p + 1) < m;
#pragma unroll
            for (int r = 0; r < R; ++r) {
                f2 dots = px0[r] * bx + px1[r] * by + px2[r] * bz;   // 2k*(x.y)
                f2 e = dots + bw + hrow[r];                          // k*(f+g-C)
                float w0 = exp2fast(e.x), w1 = exp2fast(e.y);        // n*m*P
                f2 C;
                C.x = fmaxf(fmaf(dots.x, -INV_K, pxx[r] + yy2.x), 0.0f);
                C.y = fmaxf(fmaf(dots.y, -INV_K, pxx[r] + yy2.y), 0.0f);
                wcost = fmaf(w0, C.x, fmaf(w1, C.y, wcost));
                dmn[r].x = fminf(dmn[r].x, jv0 ? C.x : BIGD);
                dmn[r].y = fminf(dmn[r].y, jv1 ? C.y : BIGD);
            }
        }
#pragma unroll
        for (int r = 0; r < R; ++r) {
            float d = wmin(fminf(dmn[r].x, dmn[r].y));
            if (r0 + r < n) chx += d;   // lane-uniform
        }
        wcost = wsum(wcost);
    }

    // ---- pass B: chamfer y->x ----
    float chy = 0.0f;
    if (r0 < m) {
        const int rp = r0 >> 1;
        f2 vx0 = YSX[rp], vx1 = YSX[rp + 1];
        f2 vy0 = YSY[rp], vy1 = YSY[rp + 1];
        f2 vz0 = YSZ[rp], vz1 = YSZ[rp + 1];
        float qy0[R] = { vx0.x * INV_TK, vx0.y * INV_TK, vx1.x * INV_TK, vx1.y * INV_TK };
        float qy1[R] = { vy0.x * INV_TK, vy0.y * INV_TK, vy1.x * INV_TK, vy1.y * INV_TK };
        float qy2[R] = { vz0.x * INV_TK, vz0.y * INV_TK, vz1.x * INV_TK, vz1.y * INV_TK };
        float qyy[R];
        f2 dmn[R];
#pragma unroll
        for (int r = 0; r < R; ++r) {
            float sx = qy0[r] * TWO_K, sy = qy1[r] * TWO_K, sz = qy2[r] * TWO_K;
            qyy[r] = fmaf(sx, sx, fmaf(sy, sy, sz * sz)) * INV_2K_SQ;
            dmn[r].x = BIGD; dmn[r].y = BIGD;
        }
        const int nst = (n + 127) >> 7;
        for (int s = 0; s < nst; ++s) {
            int p = (s << 6) + lane;
            f2 bx = XSX[p], by = XSY[p], bz = XSZ[p];
            f2 xx2 = (bx * bx + by * by + bz * bz) * INV_2K_SQ;
            bool iv0 = (2 * p)     < n;
            bool iv1 = (2 * p + 1) < n;
#pragma unroll
            for (int r = 0; r < R; ++r) {
                f2 dots = qy0[r] * bx + qy1[r] * by + qy2[r] * bz;
                f2 C;
                C.x = fmaxf(fmaf(dots.x, -INV_K, qyy[r] + xx2.x), 0.0f);
                C.y = fmaxf(fmaf(dots.y, -INV_K, qyy[r] + xx2.y), 0.0f);
                dmn[r].x = fminf(dmn[r].x, iv0 ? C.x : BIGD);
                dmn[r].y = fminf(dmn[r].y, iv1 ? C.y : BIGD);
            }
        }
#pragma unroll
        for (int r = 0; r < R; ++r) {
            float d = wmin(fminf(dmn[r].x, dmn[r].y));
            if (r0 + r < m) chy += d;
        }
    }
    __syncthreads();

    // ---- WG reduce via XSX-as-float scratch; publish parts + arrival count ----
    float* xs = (float*)XSX;
    if (lane == 0) { xs[wv] = wcost; xs[8 + wv] = chx; xs[16 + wv] = chy; }
    __syncthreads();
    if (tid == 0) {
        float cs = 0.0f, cx = 0.0f, cy = 0.0f;
        for (int w = 0; w < 8; ++w) { cs += xs[w]; cx += xs[8 + w]; cy += xs[16 + w]; }
        astoref(&parts[(b * WGB + wloc) * 4 + 0], cs);
        astoref(&parts[(b * WGB + wloc) * 4 + 1], cx);
        astoref(&parts[(b * WGB + wloc) * 4 + 2], cy);
        asm volatile("s_waitcnt vmcnt(0)" ::: "memory");
        __hip_atomic_fetch_add(cntb, 1, __ATOMIC_RELAXED, __HIP_MEMORY_SCOPE_AGENT);
    }

    // ---- batch leader polls arrivals, reduces 64 WGs; last batch finishes ----
    if (wloc == 0 && wv == 0) {
        while (aloadi(cntb) < WGB) __builtin_amdgcn_s_sleep(2);
        asm volatile("" ::: "memory");
        float cs = aloadf(&parts[(b * WGB + lane) * 4 + 0]);
        float cx = aloadf(&parts[(b * WGB + lane) * 4 + 1]);
        float cy = aloadf(&parts[(b * WGB + lane) * 4 + 2]);
        cs = wsum(cs); cx = wsum(cx); cy = wsum(cy);
        if (lane == 0) {
            float cost = cs / (nf * mf);
            astoref(&bres[b], sqrtf(fmaxf(cost, 0.0f)) + cx / nf + cy / mf);
            asm volatile("s_waitcnt vmcnt(0)" ::: "memory");
            int a = __hip_atomic_fetch_add(done, 1, __ATOMIC_RELAXED, __HIP_MEMORY_SCOPE_AGENT);
            if (a == BATCH - 1) {
                float acc = 0.0f;
                for (int i2 = 0; i2 < BATCH; ++i2) acc += aloadf(&bres[i2]);
                out[0] = acc * 0.125f;
            }
        }
    }
}

extern "C" void kernel_launch(void* const* d_in, const int* in_sizes, int n_in,
                              void* d_out, int out_size, void* d_ws, size_t ws_size,
                              hipStream_t stream) {
    const float* pred = (const float*)d_in[0];
    const float* gt   = (const float*)d_in[1];
    const int*  nlen  = (const int*)d_in[2];
    const int*  mlen  = (const int*)d_in[3];

    int*   hdr   = (int*)d_ws;            // flagF[4096], flagG[4096], cnt, done
    float* base  = (float*)d_ws + 9216;   // skip 36 KB of sync state
    float* fbuf  = base;                  // 8*2048 (u-domain f)
    float* gbuf  = fbuf + BATCH * NPTS;   // 8*2048 (u-domain g)
    float* parts = gbuf + BATCH * NPTS;   // 512*4
    float* bres  = parts + NWG * 4;       // 8
    float* out   = (float*)d_out;

    hipMemsetAsync(d_ws, 0, 36864, stream);   // zero flags/counters each call
    hipLaunchKernelGGL(pcl_kernel, dim3(NWG), dim3(TPB), 0, stream,
                       pred, gt, nlen, mlen, hdr, fbuf, gbuf, parts, bres, out);
}

// Round 12
// 767.826 us; speedup vs baseline: 1.2643x; 1.2643x over previous
//
#include <hip/hip_runtime.h>

#define BATCH 8
#define NPTS  2048
#define TPB   1024          // 16 waves/WG, 1 WG/CU (LDS-forced), 4 waves/SIMD
#define WGB   32            // workgroups per batch
#define NWG   (BATCH*WGB)   // 256 = one per CU
#define ITERS 50
#define R     4

#define KLOG2E    1442.6950408889634f    // log2(e)/eps
#define TWO_K     2885.3900817779268f    // 2*log2(e)/eps
#define INV_TK    3.4657359027997264e-4f // 1/(2k)
#define INV_K     6.931471805599453e-4f  // 1/k = eps*ln2
#define INV_2K_SQ 1.2011325347955035e-7f // 1/(2k)^2
#define AR_SCALE  -1.7328679513998632e-4f// -k/(2k)^2 = -1/(4k)
#define NEGU      -1e30f
#define BIGD      1e10f

typedef float f2 __attribute__((ext_vector_type(2)));

__device__ __forceinline__ float exp2fast(float x) { return __builtin_amdgcn_exp2f(x); }
__device__ __forceinline__ float log2fast(float x) { return __builtin_amdgcn_logf(x); }
__device__ __forceinline__ float clipf(float v)    { return fminf(fmaxf(v, -1.0f), 1.0f); }
__device__ __forceinline__ f2 bc(float x) { f2 r; r.x = x; r.y = x; return r; }

// packed fp32: ALL operands are 64-bit VGPR pairs on gfx950
__device__ __forceinline__ f2 pk_fma(f2 a, f2 b, f2 c) {
    f2 d;
    asm("v_pk_fma_f32 %0, %1, %2, %3" : "=v"(d) : "v"(a), "v"(b), "v"(c));
    return d;
}
__device__ __forceinline__ f2 pk_add(f2 a, f2 b) {
    f2 d;
    asm("v_pk_add_f32 %0, %1, %2" : "=v"(d) : "v"(a), "v"(b));
    return d;
}

// relaxed agent-scope atomics: coherent at LLC, no fences/cache maintenance
__device__ __forceinline__ float aloadf(const float* p) {
    return __hip_atomic_load(p, __ATOMIC_RELAXED, __HIP_MEMORY_SCOPE_AGENT);
}
__device__ __forceinline__ void astoref(float* p, float v) {
    __hip_atomic_store(p, v, __ATOMIC_RELAXED, __HIP_MEMORY_SCOPE_AGENT);
}
__device__ __forceinline__ int aloadi(const int* p) {
    return __hip_atomic_load(p, __ATOMIC_RELAXED, __HIP_MEMORY_SCOPE_AGENT);
}
__device__ __forceinline__ void astorei(int* p, int v) {
    __hip_atomic_store(p, v, __ATOMIC_RELAXED, __HIP_MEMORY_SCOPE_AGENT);
}
__device__ __forceinline__ f2 aloadf2(const float* p) {
    unsigned long long v = __hip_atomic_load((const unsigned long long*)p,
                                             __ATOMIC_RELAXED, __HIP_MEMORY_SCOPE_AGENT);
    union { unsigned long long u; f2 f; } c; c.u = v; return c.f;
}

__device__ __forceinline__ float wsum(float v) {
#pragma unroll
    for (int d = 1; d < 64; d <<= 1) v += __shfl_xor(v, d);
    return v;
}
__device__ __forceinline__ float wmax(float v) {
#pragma unroll
    for (int d = 1; d < 64; d <<= 1) v = fmaxf(v, __shfl_xor(v, d));
    return v;
}
__device__ __forceinline__ float wmin(float v) {
#pragma unroll
    for (int d = 1; d < 64; d <<= 1) v = fminf(v, __shfl_xor(v, d));
    return v;
}

// Fence-free sense-reversing per-batch barrier over WGB=32 workgroups.
// All WGs resident by construction (grid 256, 1 WG/CU forced by 84KB LDS).
// Pre-barrier __syncthreads drains every wave's agent-scope stores (HIP emits
// vmcnt(0) before s_barrier), so the arrival atomic orders after them.
__device__ __forceinline__ void batch_barrier(int* cnt, int* gen, int tid)
{
    __syncthreads();
    if (tid == 0) {
        asm volatile("s_waitcnt vmcnt(0)" ::: "memory");
        int g = aloadi(gen);
        int a = __hip_atomic_fetch_add(cnt, 1, __ATOMIC_RELAXED, __HIP_MEMORY_SCOPE_AGENT);
        if (a == WGB - 1) {
            astorei(cnt, 0);
            asm volatile("s_waitcnt vmcnt(0)" ::: "memory");   // reset visible first
            astorei(gen, g + 1);
        } else {
            while (aloadi(gen) == g) __builtin_amdgcn_s_sleep(1);
        }
    }
    __syncthreads();
}

// One Sinkhorn half-iteration, packed-pair LSE over planar f2 LDS columns.
// cw = staged u of the other side (NEGU-padded). Rows re-derived from own-side
// planes. Persistent log2 ref L[] + drift D[]; exact 2-pass redo on seed/NaN/
// blowup. Output: u_row = L2C - lnew published via relaxed agent stores.
__device__ __forceinline__ void half_fused_pk(
    const f2* __restrict__ cx, const f2* __restrict__ cy,
    const f2* __restrict__ cz, const f2* __restrict__ cw,
    const f2* __restrict__ rx, const f2* __restrict__ ry, const f2* __restrict__ rz,
    float* __restrict__ uout, float L2C, float* L, float* D,
    int nrows, int ncols, int r0, int lane)
{
    if (r0 >= nrows) return;
    const int nst = (ncols + 127) >> 7;   // 128 cols/step
    const int rp = r0 >> 1;
    f2 vx0 = rx[rp], vx1 = rx[rp + 1];
    f2 vy0 = ry[rp], vy1 = ry[rp + 1];
    f2 vz0 = rz[rp], vz1 = rz[rp + 1];
    f2 x0p[R] = { bc(vx0.x * INV_TK), bc(vx0.y * INV_TK), bc(vx1.x * INV_TK), bc(vx1.y * INV_TK) };
    f2 x1p[R] = { bc(vy0.x * INV_TK), bc(vy0.y * INV_TK), bc(vy1.x * INV_TK), bc(vy1.y * INV_TK) };
    f2 x2p[R] = { bc(vz0.x * INV_TK), bc(vz0.y * INV_TK), bc(vz1.x * INV_TK), bc(vz1.y * INV_TK) };

    float Lp[R];
    f2 nLp[R];
#pragma unroll
    for (int r = 0; r < R; ++r) { Lp[r] = L[r] + D[r]; nLp[r] = bc(-Lp[r]); }

    float S0[R], S1[R];
#pragma unroll
    for (int r = 0; r < R; ++r) { S0[r] = 0.0f; S1[r] = 0.0f; }

    for (int s = 0; s < nst; ++s) {
        int p = (s << 6) + lane;
        f2 bx = cx[p], by = cy[p], bz = cz[p], bw = cw[p];
#pragma unroll
        for (int r = 0; r < R; ++r) {
            f2 t = pk_fma(x2p[r], bz, bw);
            t = pk_fma(x1p[r], by, t);
            t = pk_fma(x0p[r], bx, t);
            t = pk_add(nLp[r], t);
            S0[r] += exp2fast(t.x);
            S1[r] += exp2fast(t.y);
        }
    }

    float Ssum[R];
    bool redo = false;
#pragma unroll
    for (int r = 0; r < R; ++r) {
        Ssum[r] = wsum(S0[r] + S1[r]);
        redo |= !(Ssum[r] >= 1e-30f && Ssum[r] <= 1e30f);   // 0/inf/NaN/drift
    }
    if (redo) {   // wave-uniform exact two-pass recompute
        float Mn[R];
#pragma unroll
        for (int r = 0; r < R; ++r) Mn[r] = -3.0e38f;
        for (int s = 0; s < nst; ++s) {
            int p = (s << 6) + lane;
            f2 bx = cx[p], by = cy[p], bz = cz[p], bw = cw[p];
#pragma unroll
            for (int r = 0; r < R; ++r) {
                f2 t = pk_fma(x2p[r], bz, bw);
                t = pk_fma(x1p[r], by, t);
                t = pk_fma(x0p[r], bx, t);
                Mn[r] = fmaxf(Mn[r], fmaxf(t.x, t.y));
            }
        }
#pragma unroll
        for (int r = 0; r < R; ++r) {
            Lp[r] = wmax(Mn[r]); nLp[r] = bc(-Lp[r]);
            S0[r] = 0.0f; S1[r] = 0.0f;
        }
        for (int s = 0; s < nst; ++s) {
            int p = (s << 6) + lane;
            f2 bx = cx[p], by = cy[p], bz = cz[p], bw = cw[p];
#pragma unroll
            for (int r = 0; r < R; ++r) {
                f2 t = pk_fma(x2p[r], bz, bw);
                t = pk_fma(x1p[r], by, t);
                t = pk_fma(x0p[r], bx, t);
                t = pk_add(nLp[r], t);
                S0[r] += exp2fast(t.x);
                S1[r] += exp2fast(t.y);
            }
        }
#pragma unroll
        for (int r = 0; r < R; ++r) Ssum[r] = wsum(S0[r] + S1[r]);
    }

    float uv[R];
#pragma unroll
    for (int r = 0; r < R; ++r) {
        float lnew = Lp[r] + log2fast(Ssum[r]);          // exact LSE2
        D[r] = (L[r] > 1.0e37f) ? 0.0f : (lnew - L[r]);  // drift (0 on seed)
        L[r] = lnew;
        uv[r] = L2C - lnew;                              // u-domain output
    }
    float v = uv[0];
#pragma unroll
    for (int r = 1; r < R; ++r) v = (lane == r) ? uv[r] : v;
    if (lane < R && (r0 + lane) < nrows) astoref(&uout[r0 + lane], v);
}

extern __shared__ char lds_pad[];   // 28 KB dynamic: forces 84KB/WG -> 1 WG/CU

__launch_bounds__(TPB)   // 1024 threads -> compiler caps VGPR at 128 (4 waves/SIMD)
__global__ void pcl_kernel(const float* __restrict__ pred,
                           const float* __restrict__ gt,
                           const int* __restrict__ nlen,
                           const int* __restrict__ mlen,
                           int* __restrict__ hdr,
                           float* __restrict__ fbuf,
                           float* __restrict__ gbuf,
                           float* __restrict__ parts,
                           float* __restrict__ bres,
                           float* __restrict__ out)
{
    // planar geometry (6 x 8KB) + one staging plane (8KB) = 56KB static
    __shared__ f2 XSX[NPTS/2], XSY[NPTS/2], XSZ[NPTS/2];
    __shared__ f2 YSX[NPTS/2], YSY[NPTS/2], YSZ[NPTS/2];
    __shared__ f2 WS[NPTS/2];        // alternates u_g / u_f per phase

    const int tid  = threadIdx.x;
    const int wg   = blockIdx.x;
    const int b    = wg & 7;          // batch (XCD-affine under wg%8 round-robin)
    const int wloc = wg >> 3;         // 0..31 within batch
    const int wv   = tid >> 6;        // 0..15
    const int lane = tid & 63;
    const int r0   = wloc * 64 + wv * R;   // first row (0..2044)
    const int j0   = tid << 1;             // this thread's 2 staged columns
    const int n = nlen[b];
    const int m = mlen[b];
    const float nf = (float)n, mf = (float)m;
    const float* predb = pred + (size_t)b * NPTS * 3;
    const float* gtb   = gt   + (size_t)b * NPTS * 3;
    float* fb = fbuf + b * NPTS;      // u-domain f
    float* gb = gbuf + b * NPTS;      // u-domain g
    int* cnt  = hdr + b * 16;         // 64 B apart
    int* gen  = hdr + 128 + b * 16;
    int* cntb = hdr + 256 + b * 16;
    int* done = hdr + 384;

    // stage scaled clipped geometry into planar LDS
    for (int idx = tid; idx < NPTS; idx += TPB) {
        const float* p = predb + (size_t)idx * 3;
        ((float*)XSX)[idx] = clipf(p[0]) * TWO_K;
        ((float*)XSY)[idx] = clipf(p[1]) * TWO_K;
        ((float*)XSZ)[idx] = clipf(p[2]) * TWO_K;
        const float* q = gtb + (size_t)idx * 3;
        ((float*)YSX)[idx] = clipf(q[0]) * TWO_K;
        ((float*)YSY)[idx] = clipf(q[1]) * TWO_K;
        ((float*)YSZ)[idx] = clipf(q[2]) * TWO_K;
    }
    __syncthreads();

    const float L2M = log2fast(mf);
    const float L2N = log2fast(nf);

    float Lf[R], Lg[R], Df[R], Dg[R];
#pragma unroll
    for (int r = 0; r < R; ++r) {
        Lf[r] = 3.0e38f; Lg[r] = 3.0e38f;   // sentinel: exact redo at iter 0
        Df[r] = 0.0f;    Dg[r] = 0.0f;
    }

    for (int it = 0; it < ITERS; ++it) {
        // ---- stage u_g into WS (iter 0: derive g==0 from geometry) ----
        {
            f2 w;
            if (it == 0) {
                f2 bx = YSX[tid], by = YSY[tid], bz = YSZ[tid];
                f2 s = bx * bx + by * by + bz * bz;
                w = s * AR_SCALE;
            } else {
                w = aloadf2(&gb[j0]);
            }
            if (j0     >= m) w.x = NEGU;
            if (j0 + 1 >= m) w.y = NEGU;
            WS[tid] = w;
        }
        __syncthreads();
        half_fused_pk(YSX, YSY, YSZ, WS, XSX, XSY, XSZ,
                      fb, L2M, Lf, Df, n, m, r0, lane);   // f = update(g)
        batch_barrier(cnt, gen, tid);                     // publish f batch-wide
        // ---- stage u_f into WS ----
        {
            f2 w = aloadf2(&fb[j0]);
            if (j0     >= n) w.x = NEGU;
            if (j0 + 1 >= n) w.y = NEGU;
            WS[tid] = w;
        }
        __syncthreads();
        half_fused_pk(XSX, XSY, XSZ, WS, YSX, YSY, YSZ,
                      gb, L2N, Lg, Dg, m, n, r0, lane);   // g = update(f)
        batch_barrier(cnt, gen, tid);                     // publish g batch-wide
    }

    // ---- stage final u_g for the cost pass ----
    {
        f2 w = aloadf2(&gb[j0]);
        if (j0     >= m) w.x = NEGU;
        if (j0 + 1 >= m) w.y = NEGU;
        WS[tid] = w;
    }
    __syncthreads();

    // ---- pass A: transport cost + chamfer x->y ----
    float wcost = 0.0f, chx = 0.0f;
    if (r0 < n) {
        const int rp = r0 >> 1;
        f2 vx0 = XSX[rp], vx1 = XSX[rp + 1];
        f2 vy0 = XSY[rp], vy1 = XSY[rp + 1];
        f2 vz0 = XSZ[rp], vz1 = XSZ[rp + 1];
        float px0[R] = { vx0.x * INV_TK, vx0.y * INV_TK, vx1.x * INV_TK, vx1.y * INV_TK };
        float px1[R] = { vy0.x * INV_TK, vy0.y * INV_TK, vy1.x * INV_TK, vy1.y * INV_TK };
        float px2[R] = { vz0.x * INV_TK, vz0.y * INV_TK, vz1.x * INV_TK, vz1.y * INV_TK };
        float pxx[R], hrow[R];
        f2 dmn[R];
#pragma unroll
        for (int r = 0; r < R; ++r) {
            float sx = px0[r] * TWO_K, sy = px1[r] * TWO_K, sz = px2[r] * TWO_K;
            pxx[r] = fmaf(sx, sx, fmaf(sy, sy, sz * sz)) * INV_2K_SQ;
            hrow[r] = (r0 + r < n) ? aloadf(&fb[r0 + r]) : NEGU;   // u_f directly
            dmn[r].x = BIGD; dmn[r].y = BIGD;
        }
        const int nst = (m + 127) >> 7;
        for (int s = 0; s < nst; ++s) {
            int p = (s << 6) + lane;
            f2 bx = YSX[p], by = YSY[p], bz = YSZ[p], bw = WS[p];
            f2 yy2 = (bx * bx + by * by + bz * bz) * INV_2K_SQ;
            bool jv0 = (2 * p)     < m;
            bool jv1 = (2 * p + 1) < m;
#pragma unroll
            for (int r = 0; r < R; ++r) {
                f2 dots = px0[r] * bx + px1[r] * by + px2[r] * bz;   // 2k*(x.y)
                f2 e = dots + bw + hrow[r];                          // k*(f+g-C)
                float w0 = exp2fast(e.x), w1 = exp2fast(e.y);        // n*m*P
                f2 C;
                C.x = fmaxf(fmaf(dots.x, -INV_K, pxx[r] + yy2.x), 0.0f);
                C.y = fmaxf(fmaf(dots.y, -INV_K, pxx[r] + yy2.y), 0.0f);
                wcost = fmaf(w0, C.x, fmaf(w1, C.y, wcost));
                dmn[r].x = fminf(dmn[r].x, jv0 ? C.x : BIGD);
                dmn[r].y = fminf(dmn[r].y, jv1 ? C.y : BIGD);
            }
        }
#pragma unroll
        for (int r = 0; r < R; ++r) {
            float d = wmin(fminf(dmn[r].x, dmn[r].y));
            if (r0 + r < n) chx += d;   // lane-uniform
        }
        wcost = wsum(wcost);
    }

    // ---- pass B: chamfer y->x ----
    float chy = 0.0f;
    if (r0 < m) {
        const int rp = r0 >> 1;
        f2 vx0 = YSX[rp], vx1 = YSX[rp + 1];
        f2 vy0 = YSY[rp], vy1 = YSY[rp + 1];
        f2 vz0 = YSZ[rp], vz1 = YSZ[rp + 1];
        float qy0[R] = { vx0.x * INV_TK, vx0.y * INV_TK, vx1.x * INV_TK, vx1.y * INV_TK };
        float qy1[R] = { vy0.x * INV_TK, vy0.y * INV_TK, vy1.x * INV_TK, vy1.y * INV_TK };
        float qy2[R] = { vz0.x * INV_TK, vz0.y * INV_TK, vz1.x * INV_TK, vz1.y * INV_TK };
        float qyy[R];
        f2 dmn[R];
#pragma unroll
        for (int r = 0; r < R; ++r) {
            float sx = qy0[r] * TWO_K, sy = qy1[r] * TWO_K, sz = qy2[r] * TWO_K;
            qyy[r] = fmaf(sx, sx, fmaf(sy, sy, sz * sz)) * INV_2K_SQ;
            dmn[r].x = BIGD; dmn[r].y = BIGD;
        }
        const int nst = (n + 127) >> 7;
        for (int s = 0; s < nst; ++s) {
            int p = (s << 6) + lane;
            f2 bx = XSX[p], by = XSY[p], bz = XSZ[p];
            f2 xx2 = (bx * bx + by * by + bz * bz) * INV_2K_SQ;
            bool iv0 = (2 * p)     < n;
            bool iv1 = (2 * p + 1) < n;
#pragma unroll
            for (int r = 0; r < R; ++r) {
                f2 dots = qy0[r] * bx + qy1[r] * by + qy2[r] * bz;
                f2 C;
                C.x = fmaxf(fmaf(dots.x, -INV_K, qyy[r] + xx2.x), 0.0f);
                C.y = fmaxf(fmaf(dots.y, -INV_K, qyy[r] + xx2.y), 0.0f);
                dmn[r].x = fminf(dmn[r].x, iv0 ? C.x : BIGD);
                dmn[r].y = fminf(dmn[r].y, iv1 ? C.y : BIGD);
            }
        }
#pragma unroll
        for (int r = 0; r < R; ++r) {
            float d = wmin(fminf(dmn[r].x, dmn[r].y));
            if (r0 + r < m) chy += d;
        }
    }
    __syncthreads();

    // ---- WG reduce via XSX-as-float scratch; publish parts + arrival count ----
    float* xs = (float*)XSX;
    if (lane == 0) { xs[wv] = wcost; xs[16 + wv] = chx; xs[32 + wv] = chy; }
    __syncthreads();
    if (tid == 0) {
        float cs = 0.0f, cx = 0.0f, cy = 0.0f;
        for (int w = 0; w < 16; ++w) { cs += xs[w]; cx += xs[16 + w]; cy += xs[32 + w]; }
        astoref(&parts[(b * WGB + wloc) * 4 + 0], cs);
        astoref(&parts[(b * WGB + wloc) * 4 + 1], cx);
        astoref(&parts[(b * WGB + wloc) * 4 + 2], cy);
        asm volatile("s_waitcnt vmcnt(0)" ::: "memory");
        __hip_atomic_fetch_add(cntb, 1, __ATOMIC_RELAXED, __HIP_MEMORY_SCOPE_AGENT);
    }

    // ---- batch leader polls arrivals, reduces 32 WGs; last batch finishes ----
    if (wloc == 0 && wv == 0) {
        while (aloadi(cntb) < WGB) __builtin_amdgcn_s_sleep(1);
        asm volatile("" ::: "memory");
        float cs = 0.0f, cx = 0.0f, cy = 0.0f;
        if (lane < WGB) {
            cs = aloadf(&parts[(b * WGB + lane) * 4 + 0]);
            cx = aloadf(&parts[(b * WGB + lane) * 4 + 1]);
            cy = aloadf(&parts[(b * WGB + lane) * 4 + 2]);
        }
        cs = wsum(cs); cx = wsum(cx); cy = wsum(cy);
        if (lane == 0) {
            float cost = cs / (nf * mf);
            astoref(&bres[b], sqrtf(fmaxf(cost, 0.0f)) + cx / nf + cy / mf);
            asm volatile("s_waitcnt vmcnt(0)" ::: "memory");
            int a = __hip_atomic_fetch_add(done, 1, __ATOMIC_RELAXED, __HIP_MEMORY_SCOPE_AGENT);
            if (a == BATCH - 1) {
                float acc = 0.0f;
                for (int i2 = 0; i2 < BATCH; ++i2) acc += aloadf(&bres[i2]);
                out[0] = acc * 0.125f;
            }
        }
    }
}

extern "C" void kernel_launch(void* const* d_in, const int* in_sizes, int n_in,
                              void* d_out, int out_size, void* d_ws, size_t ws_size,
                              hipStream_t stream) {
    const float* pred = (const float*)d_in[0];
    const float* gt   = (const float*)d_in[1];
    const int*  nlen  = (const int*)d_in[2];
    const int*  mlen  = (const int*)d_in[3];

    int*   hdr   = (int*)d_ws;            // cnt/gen/cntb per batch + done (2KB)
    float* base  = (float*)d_ws + 512;
    float* fbuf  = base;                  // 8*2048 (u-domain f)
    float* gbuf  = fbuf + BATCH * NPTS;   // 8*2048 (u-domain g)
    float* parts = gbuf + BATCH * NPTS;   // 256*4
    float* bres  = parts + NWG * 4;       // 8
    float* out   = (float*)d_out;

    hipMemsetAsync(d_ws, 0, 2048, stream);   // zero barrier state each call
    hipLaunchKernelGGL(pcl_kernel, dim3(NWG), dim3(TPB), 28672 /*LDS pad: 1 WG/CU*/,
                       stream, pred, gt, nlen, mlen, hdr, fbuf, gbuf, parts, bres, out);
}

// Round 13
// 743.053 us; speedup vs baseline: 1.3065x; 1.0333x over previous
//
#include <hip/hip_runtime.h>

#define BATCH 8
#define NPTS  2048
#define TPB   1024          // 16 waves/WG, 1 WG/CU (LDS-forced), 4 waves/SIMD
#define WGB   32            // workgroups per batch
#define NWG   (BATCH*WGB)   // 256 = one per CU
#define ITERS 50
#define R     4

#define KLOG2E    1442.6950408889634f    // log2(e)/eps
#define TWO_K     2885.3900817779268f    // 2*log2(e)/eps
#define INV_TK    3.4657359027997264e-4f // 1/(2k)
#define INV_K     6.931471805599453e-4f  // 1/k = eps*ln2
#define INV_2K_SQ 1.2011325347955035e-7f // 1/(2k)^2
#define AR_SCALE  -1.7328679513998632e-4f// -k/(2k)^2 = -1/(4k)
#define NEGU      -1e30f
#define BIGD      1e10f

typedef float f2 __attribute__((ext_vector_type(2)));

__device__ __forceinline__ float exp2fast(float x) { return __builtin_amdgcn_exp2f(x); }
__device__ __forceinline__ float log2fast(float x) { return __builtin_amdgcn_logf(x); }
__device__ __forceinline__ float clipf(float v)    { return fminf(fmaxf(v, -1.0f), 1.0f); }
__device__ __forceinline__ f2 bc(float x) { f2 r; r.x = x; r.y = x; return r; }

// packed fp32: ALL operands are 64-bit VGPR pairs on gfx950
__device__ __forceinline__ f2 pk_fma(f2 a, f2 b, f2 c) {
    f2 d;
    asm("v_pk_fma_f32 %0, %1, %2, %3" : "=v"(d) : "v"(a), "v"(b), "v"(c));
    return d;
}
__device__ __forceinline__ f2 pk_add(f2 a, f2 b) {
    f2 d;
    asm("v_pk_add_f32 %0, %1, %2" : "=v"(d) : "v"(a), "v"(b));
    return d;
}

// relaxed agent-scope atomics: coherent at LLC, no fences/cache maintenance
__device__ __forceinline__ float aloadf(const float* p) {
    return __hip_atomic_load(p, __ATOMIC_RELAXED, __HIP_MEMORY_SCOPE_AGENT);
}
__device__ __forceinline__ void astoref(float* p, float v) {
    __hip_atomic_store(p, v, __ATOMIC_RELAXED, __HIP_MEMORY_SCOPE_AGENT);
}
__device__ __forceinline__ int aloadi(const int* p) {
    return __hip_atomic_load(p, __ATOMIC_RELAXED, __HIP_MEMORY_SCOPE_AGENT);
}
__device__ __forceinline__ void astorei(int* p, int v) {
    __hip_atomic_store(p, v, __ATOMIC_RELAXED, __HIP_MEMORY_SCOPE_AGENT);
}
__device__ __forceinline__ f2 aloadf2(const float* p) {
    unsigned long long v = __hip_atomic_load((const unsigned long long*)p,
                                             __ATOMIC_RELAXED, __HIP_MEMORY_SCOPE_AGENT);
    union { unsigned long long u; f2 f; } c; c.u = v; return c.f;
}

__device__ __forceinline__ float wsum(float v) {
#pragma unroll
    for (int d = 1; d < 64; d <<= 1) v += __shfl_xor(v, d);
    return v;
}
__device__ __forceinline__ float wmax(float v) {
#pragma unroll
    for (int d = 1; d < 64; d <<= 1) v = fmaxf(v, __shfl_xor(v, d));
    return v;
}
__device__ __forceinline__ float wmin(float v) {
#pragma unroll
    for (int d = 1; d < 64; d <<= 1) v = fminf(v, __shfl_xor(v, d));
    return v;
}

// Monotonic-epoch fence-free barrier over WGB=32 workgroups. Counters never
// reset: arrival e is complete when cnt reaches WGB*e; last arriver stores
// gen = e. All WGs resident by construction (grid 256, 1 WG/CU via 84KB LDS).
// The preceding __syncthreads drains every wave's vmcnt (HIP emits
// vmcnt(0) before s_barrier), so arrivals order after all agent stores.
__device__ __forceinline__ void batch_barrier(int* cnt, int* gen, int e, int tid)
{
    __syncthreads();
    if (tid == 0) {
        int a = __hip_atomic_fetch_add(cnt, 1, __ATOMIC_RELAXED, __HIP_MEMORY_SCOPE_AGENT);
        if (a == WGB * e - 1) {
            astorei(gen, e);                       // release: single store, no reset
        } else {
            while (aloadi(gen) < e) __builtin_amdgcn_s_sleep(1);
        }
    }
    __syncthreads();
}

// One Sinkhorn half-iteration, packed-pair LSE over planar f2 LDS columns.
// Row broadcast fragments (x0p/x1p/x2p) are PERSISTENT registers hoisted out
// of the loop (geometry is constant). Persistent log2 ref L[] + drift D[];
// exact 2-pass redo on seed/NaN/blowup. Publishes u = L2C - lnew.
__device__ __forceinline__ void half_fused_pk(
    const f2* __restrict__ cx, const f2* __restrict__ cy,
    const f2* __restrict__ cz, const f2* __restrict__ cw,
    const f2* x0p, const f2* x1p, const f2* x2p,
    float* __restrict__ uout, float L2C, float* L, float* D,
    int nrows, int ncols, int r0, int lane)
{
    if (r0 >= nrows) return;
    const int nst = (ncols + 127) >> 7;   // 128 cols/step

    float Lp[R];
    f2 nLp[R];
#pragma unroll
    for (int r = 0; r < R; ++r) { Lp[r] = L[r] + D[r]; nLp[r] = bc(-Lp[r]); }

    float S0[R], S1[R];
#pragma unroll
    for (int r = 0; r < R; ++r) { S0[r] = 0.0f; S1[r] = 0.0f; }

    for (int s = 0; s < nst; ++s) {
        int p = (s << 6) + lane;
        f2 bx = cx[p], by = cy[p], bz = cz[p], bw = cw[p];
#pragma unroll
        for (int r = 0; r < R; ++r) {
            f2 t = pk_fma(x2p[r], bz, bw);
            t = pk_fma(x1p[r], by, t);
            t = pk_fma(x0p[r], bx, t);
            t = pk_add(nLp[r], t);
            S0[r] += exp2fast(t.x);
            S1[r] += exp2fast(t.y);
        }
    }

    float Ssum[R];
    bool redo = false;
#pragma unroll
    for (int r = 0; r < R; ++r) {
        Ssum[r] = wsum(S0[r] + S1[r]);
        redo |= !(Ssum[r] >= 1e-30f && Ssum[r] <= 1e30f);   // 0/inf/NaN/drift
    }
    if (redo) {   // wave-uniform exact two-pass recompute
        float Mn[R];
#pragma unroll
        for (int r = 0; r < R; ++r) Mn[r] = -3.0e38f;
        for (int s = 0; s < nst; ++s) {
            int p = (s << 6) + lane;
            f2 bx = cx[p], by = cy[p], bz = cz[p], bw = cw[p];
#pragma unroll
            for (int r = 0; r < R; ++r) {
                f2 t = pk_fma(x2p[r], bz, bw);
                t = pk_fma(x1p[r], by, t);
                t = pk_fma(x0p[r], bx, t);
                Mn[r] = fmaxf(Mn[r], fmaxf(t.x, t.y));
            }
        }
#pragma unroll
        for (int r = 0; r < R; ++r) {
            Lp[r] = wmax(Mn[r]); nLp[r] = bc(-Lp[r]);
            S0[r] = 0.0f; S1[r] = 0.0f;
        }
        for (int s = 0; s < nst; ++s) {
            int p = (s << 6) + lane;
            f2 bx = cx[p], by = cy[p], bz = cz[p], bw = cw[p];
#pragma unroll
            for (int r = 0; r < R; ++r) {
                f2 t = pk_fma(x2p[r], bz, bw);
                t = pk_fma(x1p[r], by, t);
                t = pk_fma(x0p[r], bx, t);
                t = pk_add(nLp[r], t);
                S0[r] += exp2fast(t.x);
                S1[r] += exp2fast(t.y);
            }
        }
#pragma unroll
        for (int r = 0; r < R; ++r) Ssum[r] = wsum(S0[r] + S1[r]);
    }

    float uv[R];
#pragma unroll
    for (int r = 0; r < R; ++r) {
        float lnew = Lp[r] + log2fast(Ssum[r]);          // exact LSE2
        D[r] = (L[r] > 1.0e37f) ? 0.0f : (lnew - L[r]);  // drift (0 on seed)
        L[r] = lnew;
        uv[r] = L2C - lnew;                              // u-domain output
    }
    float v = uv[0];
#pragma unroll
    for (int r = 1; r < R; ++r) v = (lane == r) ? uv[r] : v;
    if (lane < R && (r0 + lane) < nrows) astoref(&uout[r0 + lane], v);
}

extern __shared__ char lds_pad[];   // 28 KB dynamic: forces 84KB/WG -> 1 WG/CU

__launch_bounds__(TPB)   // 1024 threads -> 4 waves/SIMD -> 128 VGPR budget
__global__ void pcl_kernel(const float* __restrict__ pred,
                           const float* __restrict__ gt,
                           const int* __restrict__ nlen,
                           const int* __restrict__ mlen,
                           int* __restrict__ hdr,
                           float* __restrict__ fbuf,
                           float* __restrict__ gbuf,
                           float* __restrict__ parts,
                           float* __restrict__ bres,
                           float* __restrict__ out)
{
    // planar geometry (6 x 8KB) + one staging plane (8KB) = 56KB static
    __shared__ f2 XSX[NPTS/2], XSY[NPTS/2], XSZ[NPTS/2];
    __shared__ f2 YSX[NPTS/2], YSY[NPTS/2], YSZ[NPTS/2];
    __shared__ f2 WS[NPTS/2];        // alternates u_g / u_f per phase

    const int tid  = threadIdx.x;
    const int wg   = blockIdx.x;
    const int b    = wg & 7;          // batch (XCD-affine under wg%8 round-robin)
    const int wloc = wg >> 3;         // 0..31 within batch
    const int wv   = tid >> 6;        // 0..15
    const int lane = tid & 63;
    const int r0   = wloc * 64 + wv * R;   // first row (0..2044)
    const int j0   = tid << 1;             // this thread's 2 staged columns
    const int n = nlen[b];
    const int m = mlen[b];
    const float nf = (float)n, mf = (float)m;
    const float* predb = pred + (size_t)b * NPTS * 3;
    const float* gtb   = gt   + (size_t)b * NPTS * 3;
    float* fb = fbuf + b * NPTS;      // u-domain f
    float* gb = gbuf + b * NPTS;      // u-domain g
    int* cnt  = hdr + b * 16;         // 64 B apart
    int* gen  = hdr + 128 + b * 16;
    int* cntb = hdr + 256 + b * 16;
    int* done = hdr + 384;

    // stage scaled clipped geometry into planar LDS
    for (int idx = tid; idx < NPTS; idx += TPB) {
        const float* p = predb + (size_t)idx * 3;
        ((float*)XSX)[idx] = clipf(p[0]) * TWO_K;
        ((float*)XSY)[idx] = clipf(p[1]) * TWO_K;
        ((float*)XSZ)[idx] = clipf(p[2]) * TWO_K;
        const float* q = gtb + (size_t)idx * 3;
        ((float*)YSX)[idx] = clipf(q[0]) * TWO_K;
        ((float*)YSY)[idx] = clipf(q[1]) * TWO_K;
        ((float*)YSZ)[idx] = clipf(q[2]) * TWO_K;
    }
    __syncthreads();

    const float L2M = log2fast(mf);
    const float L2N = log2fast(nf);

    // hoisted persistent row broadcast fragments (geometry is loop-invariant)
    const int rp = r0 >> 1;
    f2 fx0p[R], fx1p[R], fx2p[R];     // f-half rows (x cloud)
    f2 gy0p[R], gy1p[R], gy2p[R];     // g-half rows (y cloud)
    {
        f2 a0 = XSX[rp], a1 = XSX[rp + 1];
        f2 b0 = XSY[rp], b1 = XSY[rp + 1];
        f2 c0 = XSZ[rp], c1 = XSZ[rp + 1];
        fx0p[0] = bc(a0.x * INV_TK); fx0p[1] = bc(a0.y * INV_TK);
        fx0p[2] = bc(a1.x * INV_TK); fx0p[3] = bc(a1.y * INV_TK);
        fx1p[0] = bc(b0.x * INV_TK); fx1p[1] = bc(b0.y * INV_TK);
        fx1p[2] = bc(b1.x * INV_TK); fx1p[3] = bc(b1.y * INV_TK);
        fx2p[0] = bc(c0.x * INV_TK); fx2p[1] = bc(c0.y * INV_TK);
        fx2p[2] = bc(c1.x * INV_TK); fx2p[3] = bc(c1.y * INV_TK);
        f2 d0 = YSX[rp], d1 = YSX[rp + 1];
        f2 e0 = YSY[rp], e1 = YSY[rp + 1];
        f2 f0 = YSZ[rp], f1 = YSZ[rp + 1];
        gy0p[0] = bc(d0.x * INV_TK); gy0p[1] = bc(d0.y * INV_TK);
        gy0p[2] = bc(d1.x * INV_TK); gy0p[3] = bc(d1.y * INV_TK);
        gy1p[0] = bc(e0.x * INV_TK); gy1p[1] = bc(e0.y * INV_TK);
        gy1p[2] = bc(e1.x * INV_TK); gy1p[3] = bc(e1.y * INV_TK);
        gy2p[0] = bc(f0.x * INV_TK); gy2p[1] = bc(f0.y * INV_TK);
        gy2p[2] = bc(f1.x * INV_TK); gy2p[3] = bc(f1.y * INV_TK);
    }

    float Lf[R], Lg[R], Df[R], Dg[R];
#pragma unroll
    for (int r = 0; r < R; ++r) {
        Lf[r] = 3.0e38f; Lg[r] = 3.0e38f;   // sentinel: exact redo at iter 0
        Df[r] = 0.0f;    Dg[r] = 0.0f;
    }

    int ep = 0;   // barrier epoch (monotone)
    for (int it = 0; it < ITERS; ++it) {
        // ---- stage u_g into WS (iter 0: derive g==0 from geometry) ----
        {
            f2 w;
            if (it == 0) {
                f2 bx = YSX[tid], by = YSY[tid], bz = YSZ[tid];
                f2 s = bx * bx + by * by + bz * bz;
                w = s * AR_SCALE;
            } else {
                w = aloadf2(&gb[j0]);
            }
            if (j0     >= m) w.x = NEGU;
            if (j0 + 1 >= m) w.y = NEGU;
            WS[tid] = w;
        }
        __syncthreads();
        half_fused_pk(YSX, YSY, YSZ, WS, fx0p, fx1p, fx2p,
                      fb, L2M, Lf, Df, n, m, r0, lane);   // f = update(g)
        batch_barrier(cnt, gen, ++ep, tid);               // publish f batch-wide
        // ---- stage u_f into WS ----
        {
            f2 w = aloadf2(&fb[j0]);
            if (j0     >= n) w.x = NEGU;
            if (j0 + 1 >= n) w.y = NEGU;
            WS[tid] = w;
        }
        __syncthreads();
        half_fused_pk(XSX, XSY, XSZ, WS, gy0p, gy1p, gy2p,
                      gb, L2N, Lg, Dg, m, n, r0, lane);   // g = update(f)
        batch_barrier(cnt, gen, ++ep, tid);               // publish g batch-wide
    }

    // ---- stage final u_g for the cost pass ----
    {
        f2 w = aloadf2(&gb[j0]);
        if (j0     >= m) w.x = NEGU;
        if (j0 + 1 >= m) w.y = NEGU;
        WS[tid] = w;
    }
    __syncthreads();

    // ---- pass A: transport cost + chamfer x->y ----
    float wcost = 0.0f, chx = 0.0f;
    if (r0 < n) {
        float px0[R] = { fx0p[0].x, fx0p[1].x, fx0p[2].x, fx0p[3].x };
        float px1[R] = { fx1p[0].x, fx1p[1].x, fx1p[2].x, fx1p[3].x };
        float px2[R] = { fx2p[0].x, fx2p[1].x, fx2p[2].x, fx2p[3].x };
        float pxx[R], hrow[R];
        f2 dmn[R];
#pragma unroll
        for (int r = 0; r < R; ++r) {
            float sx = px0[r] * TWO_K, sy = px1[r] * TWO_K, sz = px2[r] * TWO_K;
            pxx[r] = fmaf(sx, sx, fmaf(sy, sy, sz * sz)) * INV_2K_SQ;
            hrow[r] = (r0 + r < n) ? aloadf(&fb[r0 + r]) : NEGU;   // u_f directly
            dmn[r].x = BIGD; dmn[r].y = BIGD;
        }
        const int nst = (m + 127) >> 7;
        for (int s = 0; s < nst; ++s) {
            int p = (s << 6) + lane;
            f2 bx = YSX[p], by = YSY[p], bz = YSZ[p], bw = WS[p];
            f2 yy2 = (bx * bx + by * by + bz * bz) * INV_2K_SQ;
            bool jv0 = (2 * p)     < m;
            bool jv1 = (2 * p + 1) < m;
#pragma unroll
            for (int r = 0; r < R; ++r) {
                f2 dots = px0[r] * bx + px1[r] * by + px2[r] * bz;   // 2k*(x.y)
                f2 e = dots + bw + hrow[r];                          // k*(f+g-C)
                float w0 = exp2fast(e.x), w1 = exp2fast(e.y);        // n*m*P
                f2 C;
                C.x = fmaxf(fmaf(dots.x, -INV_K, pxx[r] + yy2.x), 0.0f);
                C.y = fmaxf(fmaf(dots.y, -INV_K, pxx[r] + yy2.y), 0.0f);
                wcost = fmaf(w0, C.x, fmaf(w1, C.y, wcost));
                dmn[r].x = fminf(dmn[r].x, jv0 ? C.x : BIGD);
                dmn[r].y = fminf(dmn[r].y, jv1 ? C.y : BIGD);
            }
        }
#pragma unroll
        for (int r = 0; r < R; ++r) {
            float d = wmin(fminf(dmn[r].x, dmn[r].y));
            if (r0 + r < n) chx += d;   // lane-uniform
        }
        wcost = wsum(wcost);
    }

    // ---- pass B: chamfer y->x ----
    float chy = 0.0f;
    if (r0 < m) {
        float qy0[R] = { gy0p[0].x, gy0p[1].x, gy0p[2].x, gy0p[3].x };
        float qy1[R] = { gy1p[0].x, gy1p[1].x, gy1p[2].x, gy1p[3].x };
        float qy2[R] = { gy2p[0].x, gy2p[1].x, gy2p[2].x, gy2p[3].x };
        float qyy[R];
        f2 dmn[R];
#pragma unroll
        for (int r = 0; r < R; ++r) {
            float sx = qy0[r] * TWO_K, sy = qy1[r] * TWO_K, sz = qy2[r] * TWO_K;
            qyy[r] = fmaf(sx, sx, fmaf(sy, sy, sz * sz)) * INV_2K_SQ;
            dmn[r].x = BIGD; dmn[r].y = BIGD;
        }
        const int nst = (n + 127) >> 7;
        for (int s = 0; s < nst; ++s) {
            int p = (s << 6) + lane;
            f2 bx = XSX[p], by = XSY[p], bz = XSZ[p];
            f2 xx2 = (bx * bx + by * by + bz * bz) * INV_2K_SQ;
            bool iv0 = (2 * p)     < n;
            bool iv1 = (2 * p + 1) < n;
#pragma unroll
            for (int r = 0; r < R; ++r) {
                f2 dots = qy0[r] * bx + qy1[r] * by + qy2[r] * bz;
                f2 C;
                C.x = fmaxf(fmaf(dots.x, -INV_K, qyy[r] + xx2.x), 0.0f);
                C.y = fmaxf(fmaf(dots.y, -INV_K, qyy[r] + xx2.y), 0.0f);
                dmn[r].x = fminf(dmn[r].x, iv0 ? C.x : BIGD);
                dmn[r].y = fminf(dmn[r].y, iv1 ? C.y : BIGD);
            }
        }
#pragma unroll
        for (int r = 0; r < R; ++r) {
            float d = wmin(fminf(dmn[r].x, dmn[r].y));
            if (r0 + r < m) chy += d;
        }
    }
    __syncthreads();

    // ---- WG reduce via XSX-as-float scratch; publish parts + arrival count ----
    float* xs = (float*)XSX;
    if (lane == 0) { xs[wv] = wcost; xs[16 + wv] = chx; xs[32 + wv] = chy; }
    __syncthreads();
    if (tid == 0) {
        float cs = 0.0f, cx = 0.0f, cy = 0.0f;
        for (int w = 0; w < 16; ++w) { cs += xs[w]; cx += xs[16 + w]; cy += xs[32 + w]; }
        astoref(&parts[(b * WGB + wloc) * 4 + 0], cs);
        astoref(&parts[(b * WGB + wloc) * 4 + 1], cx);
        astoref(&parts[(b * WGB + wloc) * 4 + 2], cy);
        asm volatile("s_waitcnt vmcnt(0)" ::: "memory");
        __hip_atomic_fetch_add(cntb, 1, __ATOMIC_RELAXED, __HIP_MEMORY_SCOPE_AGENT);
    }

    // ---- batch leader polls arrivals, reduces 32 WGs; last batch finishes ----
    if (wloc == 0 && wv == 0) {
        while (aloadi(cntb) < WGB) __builtin_amdgcn_s_sleep(1);
        asm volatile("" ::: "memory");
        float cs = 0.0f, cx = 0.0f, cy = 0.0f;
        if (lane < WGB) {
            cs = aloadf(&parts[(b * WGB + lane) * 4 + 0]);
            cx = aloadf(&parts[(b * WGB + lane) * 4 + 1]);
            cy = aloadf(&parts[(b * WGB + lane) * 4 + 2]);
        }
        cs = wsum(cs); cx = wsum(cx); cy = wsum(cy);
        if (lane == 0) {
            float cost = cs / (nf * mf);
            astoref(&bres[b], sqrtf(fmaxf(cost, 0.0f)) + cx / nf + cy / mf);
            asm volatile("s_waitcnt vmcnt(0)" ::: "memory");
            int a = __hip_atomic_fetch_add(done, 1, __ATOMIC_RELAXED, __HIP_MEMORY_SCOPE_AGENT);
            if (a == BATCH - 1) {
                float acc = 0.0f;
                for (int i2 = 0; i2 < BATCH; ++i2) acc += aloadf(&bres[i2]);
                out[0] = acc * 0.125f;
            }
        }
    }
}

extern "C" void kernel_launch(void* const* d_in, const int* in_sizes, int n_in,
                              void* d_out, int out_size, void* d_ws, size_t ws_size,
                              hipStream_t stream) {
    const float* pred = (const float*)d_in[0];
    const float* gt   = (const float*)d_in[1];
    const int*  nlen  = (const int*)d_in[2];
    const int*  mlen  = (const int*)d_in[3];

    int*   hdr   = (int*)d_ws;            // cnt/gen/cntb per batch + done (2KB)
    float* base  = (float*)d_ws + 512;
    float* fbuf  = base;                  // 8*2048 (u-domain f)
    float* gbuf  = fbuf + BATCH * NPTS;   // 8*2048 (u-domain g)
    float* parts = gbuf + BATCH * NPTS;   // 256*4
    float* bres  = parts + NWG * 4;       // 8
    float* out   = (float*)d_out;

    hipMemsetAsync(d_ws, 0, 2048, stream);   // zero barrier state each call
    hipLaunchKernelGGL(pcl_kernel, dim3(NWG), dim3(TPB), 28672 /*LDS pad: 1 WG/CU*/,
                       stream, pred, gt, nlen, mlen, hdr, fbuf, gbuf, parts, bres, out);
}